// Round 14
// baseline (135.339 us; speedup 1.0000x reference)
//
#include <hip/hip_runtime.h>
#include <hip/hip_bf16.h>

// LSTM_71382356459716 R13: 8 chains/SIMD (R12 skeleton, 8-wave blocks).
// Cross-round invariant: wall ~57us does NOT track trans count (R1 10/tuple vs
// R9 7/tuple: flat), VALU count, or barrier count -- but every ~57us config
// has exactly 4 independent recurrence chains per SIMD, and R11's 1 chain =
// 72.6us. Diagnosis: latency-bound recurrence (per-chain exposed latency
// ~1250cyc/step: LDS round-trip + MFMA dep chain + trans dep chain), only
// partially overlapped at 4 chains. Fix: 512-thread blocks, 8 waves, wave
// owns 2 M-tiles per cohort x 2 cohorts; grid 512 -> 2 blocks/CU = 4 waves/
// SIMD x 2 cohorts = 8 chains/SIMD. Per-wave VGPR demand ~100 < 128 @
// waves_per_eu(4,4) -> no spill. Store perm: p = 8w+2q+e <-> unit
// u = 8*(p>>3)+4*(p&1)+((p>>1)&3), baked into prep + FC.
// Numerics = R9/R12: exp2-prescaled weights (log2e / 2log2e), c in scaled
// units, rcp groups {i,f,g}+{o,c} (7 trans/tuple), bias col 28 vs
// constant-1 x col, double-buffered 104-short rows, 1 barrier/step.

namespace {
constexpr int B_TOT   = 16384;
constexpr int T_STEPS = 28;
constexpr int IN_DIM  = 28;
constexpr int HID     = 64;
constexpr int OUT_DIM = 10;
constexpr int RPC     = 16;    // rows per cohort
constexpr int NCOH    = 2;     // cohorts per block -> 32 rows/block
constexpr int THREADS = 512;   // 8 waves
constexpr int KP      = 104;   // row stride in shorts (208 B, odd*16B)
constexpr int XROW    = T_STEPS * IN_DIM;  // 784 floats per batch row
constexpr int WS_ELEMS = 48 * 64 * 8;      // 48 KB frag-ordered weights
}

typedef __attribute__((ext_vector_type(8))) short short8v;   // 8 bf16
typedef __attribute__((ext_vector_type(4))) short short4v;
typedef __attribute__((ext_vector_type(4))) float float4v;

__device__ __forceinline__ short f2bf_cold(float f) {
  union { float f; unsigned u; } v; v.f = f;
  unsigned r = v.u + 0x7FFFu + ((v.u >> 16) & 1u);
  return (short)(r >> 16);
}
__device__ __forceinline__ float bf2f(short s) {
  union { unsigned u; float f; } v; v.u = ((unsigned)(unsigned short)s) << 16;
  return v.f;
}
__device__ __forceinline__ unsigned pk2(float a, float b) {  // 2xf32->bf16x2
  __hip_bfloat162 h = __float22bfloat162_rn(float2{a, b});
  union { __hip_bfloat162 h; unsigned u; } cv; cv.h = h; return cv.u;
}

// ---- setup: permute+prescale weights into MFMA A-frag order ----------------
// Frag f = mt*3 + kc (mt 0..15), lane l, elem j:
//   ws[(f*64+l)*8+j] = bf16( scale(type) * Araw[m=16*mt+(l&15)][k] ),
//   k = kc*32 + (l>>4)*8 + j; gate row g = (m&3)*64 + (m>>2);
// scale = log2e (i,f,o) / 2*log2e (g). k<28 -> W_ih; k==28 -> b_ih+b_hh;
// 29..31 -> 0; k>=32 -> W_hh col through sigma^-1:
//   p = k-32, u = 8*(p>>3) + 4*(p&1) + ((p>>1)&3).
__global__ void lstm_prep(const float* __restrict__ W_ih,
                          const float* __restrict__ W_hh,
                          const float* __restrict__ b_ih,
                          const float* __restrict__ b_hh,
                          unsigned short* __restrict__ ws) {
  int idx = blockIdx.x * blockDim.x + threadIdx.x;
  if (idx >= WS_ELEMS) return;
  int j  = idx & 7;
  int l  = (idx >> 3) & 63;
  int fk = idx >> 9;            // mt*3 + kc
  int kc = fk % 3;
  int mt = fk / 3;
  int m  = 16 * mt + (l & 15);
  int unit = m >> 2, type = m & 3;
  int g  = type * 64 + unit;
  int k  = kc * 32 + (l >> 4) * 8 + j;
  float v = 0.0f;
  if (k < IN_DIM)        v = W_ih[g * IN_DIM + k];
  else if (k == IN_DIM)  v = b_ih[g] + b_hh[g];
  else if (k >= 32) {
    int p = k - 32;
    int u = 8 * (p >> 3) + 4 * (p & 1) + ((p >> 1) & 3);   // sigma^-1
    v = W_hh[g * HID + u];
  }
  v *= (type == 2) ? 2.8853900817779268f : 1.4426950408889634f;
  ws[idx] = (unsigned short)f2bf_cold(v);
}

__device__ __forceinline__ void act_tuple(const float4v g4, float& c,
                                          float& hv) {
  float Ei = __builtin_amdgcn_exp2f(-g4[0]);
  float Ef = __builtin_amdgcn_exp2f(-g4[1]);
  float Eg = __builtin_amdgcn_exp2f(-g4[2]);
  float di = 1.0f + Ei, df = 1.0f + Ef, dg = 1.0f + Eg;
  float t1 = di * df;
  float r1 = __builtin_amdgcn_rcpf(t1 * dg);
  float iv = r1 * (df * dg);
  float fv = r1 * (di * dg);
  float gnum = fmaf(-Eg, 2.8853900817779268f, 2.8853900817779268f);
  float gv = (r1 * t1) * gnum;
  float cn = fmaf(fv, c, iv * gv);
  c = cn;
  float ct = fminf(fmaxf(cn, -44.0f), 44.0f);
  float Eo = __builtin_amdgcn_exp2f(-g4[3]);
  float Ec = __builtin_amdgcn_exp2f(-ct);
  float dn = 1.0f + Eo, dc = 1.0f + Ec;
  float r2 = __builtin_amdgcn_rcpf(dn * dc);
  float ov = r2 * dc;                 // sigma(o)
  float tc = (r2 * dn) * (1.0f - Ec); // tanh(c)
  hv = ov * tc;
}

__global__ __attribute__((amdgpu_flat_work_group_size(THREADS, THREADS),
                          amdgpu_waves_per_eu(4, 4)))
void lstm_mfma13(const float* __restrict__ x,
                 const unsigned short* __restrict__ wfrag,
                 const float* __restrict__ W_fc,
                 const float* __restrict__ b_fc, float* __restrict__ out) {
  // [cohort][buf][row][k]: k 0..27 x, 28 = 1.0, 32..95 h (permuted). 13 KB.
  __shared__ short hs[NCOH][2][RPC][KP];

  const int tid  = threadIdx.x;
  const int lane = tid & 63;
  const int w    = tid >> 6;      // wave 0..7 -> M-tiles 2w, 2w+1
  const int l15  = lane & 15;
  const int q    = lane >> 4;     // 0..3
  const int b0   = blockIdx.x * (NCOH * RPC);   // 32 rows per block

  // ---- stationary A: 6 coalesced 16B loads per lane (shared by cohorts) ----
  short8v a[2][3];
#pragma unroll
  for (int i = 0; i < 2; ++i)
#pragma unroll
    for (int kc = 0; kc < 3; ++kc)
      a[i][kc] = *(const short8v*)&wfrag[((((2 * w + i) * 3) + kc) * 64 + lane) * 8];

  // zero both cohorts' buffers, set constant bias columns
  for (int idx = tid; idx < NCOH * 2 * RPC * KP; idx += THREADS)
    (&hs[0][0][0][0])[idx] = 0;
  __syncthreads();
  if (tid < NCOH * 2 * RPC) {
    int coh = tid >> 5, buf = (tid >> 4) & 1, r = tid & 15;
    hs[coh][buf][r][IN_DIM] = (short)0x3F80;  // bf16 1.0
  }

  // ---- x staging: 224 stager lanes (lanes 0..27 of each wave) --------------
  const int  s  = w * 28 + lane;        // 0..223 for lane<28
  const bool stager = (lane < 28);
  const int  sr = s / 7;                // block-row 0..31
  const int  sc = s - 7 * sr;           // col-group 0..6
  const int  scoh = sr >> 4, srow = sr & 15;
  const float* xptr = x + (size_t)(b0 + sr) * XROW + sc * 4;

  float4 xfly = {0.f, 0.f, 0.f, 0.f};
  if (stager) {
    float4 x0 = *(const float4*)xptr;
    short4v sv;
    unsigned plo = pk2(x0.x, x0.y), phi = pk2(x0.z, x0.w);
    sv[0] = (short)(plo & 0xFFFF); sv[1] = (short)(plo >> 16);
    sv[2] = (short)(phi & 0xFFFF); sv[3] = (short)(phi >> 16);
    *(short4v*)&hs[scoh][0][srow][sc * 4] = sv;
    xfly = *(const float4*)(xptr + 1 * IN_DIM);   // x_1, consumed at t=0
  }
  __syncthreads();

  float c_state[NCOH][2] = {{0.f, 0.f}, {0.f, 0.f}};

  for (int t = 0; t < T_STEPS; ++t) {
    const int cur = t & 1, nxt = cur ^ 1;

    // B-frags for BOTH cohorts up front (independent ds_reads)
    short8v bfA0 = *(const short8v*)&hs[0][cur][l15][q * 8];
    short8v bfA1 = *(const short8v*)&hs[0][cur][l15][32 + q * 8];
    short8v bfA2 = *(const short8v*)&hs[0][cur][l15][64 + q * 8];
    short8v bfB0 = *(const short8v*)&hs[1][cur][l15][q * 8];
    short8v bfB1 = *(const short8v*)&hs[1][cur][l15][32 + q * 8];
    short8v bfB2 = *(const short8v*)&hs[1][cur][l15][64 + q * 8];

    // stager: store x_{t+1} (loaded a full step ago), issue load of x_{t+2}
    if (stager) {
      if (t + 1 < T_STEPS) {
        short4v sv;
        unsigned plo = pk2(xfly.x, xfly.y), phi = pk2(xfly.z, xfly.w);
        sv[0] = (short)(plo & 0xFFFF); sv[1] = (short)(plo >> 16);
        sv[2] = (short)(phi & 0xFFFF); sv[3] = (short)(phi >> 16);
        *(short4v*)&hs[scoh][nxt][srow][sc * 4] = sv;
      }
      if (t + 2 < T_STEPS)
        xfly = *(const float4*)(xptr + (t + 2) * IN_DIM);
    }

    const float4v zero4 = {0.f, 0.f, 0.f, 0.f};
    float4v accA[2], accB[2];
#pragma unroll
    for (int i = 0; i < 2; ++i)
      accA[i] = __builtin_amdgcn_mfma_f32_16x16x32_bf16(a[i][0], bfA0, zero4, 0, 0, 0);
#pragma unroll
    for (int i = 0; i < 2; ++i)
      accA[i] = __builtin_amdgcn_mfma_f32_16x16x32_bf16(a[i][1], bfA1, accA[i], 0, 0, 0);
#pragma unroll
    for (int i = 0; i < 2; ++i)
      accA[i] = __builtin_amdgcn_mfma_f32_16x16x32_bf16(a[i][2], bfA2, accA[i], 0, 0, 0);
#pragma unroll
    for (int i = 0; i < 2; ++i)
      accB[i] = __builtin_amdgcn_mfma_f32_16x16x32_bf16(a[i][0], bfB0, zero4, 0, 0, 0);
#pragma unroll
    for (int i = 0; i < 2; ++i)
      accB[i] = __builtin_amdgcn_mfma_f32_16x16x32_bf16(a[i][1], bfB1, accB[i], 0, 0, 0);
#pragma unroll
    for (int i = 0; i < 2; ++i)
      accB[i] = __builtin_amdgcn_mfma_f32_16x16x32_bf16(a[i][2], bfB2, accB[i], 0, 0, 0);

    // activations + h stores: tuples (cohort, i) -> unit u = 8w + 4i + q
    {
      float hv[2];
#pragma unroll
      for (int i = 0; i < 2; ++i) act_tuple(accA[i], c_state[0][i], hv[i]);
      unsigned p01 = pk2(hv[0], hv[1]);
      *(unsigned*)&hs[0][nxt][l15][32 + 8 * w + 2 * q] = p01;
    }
    {
      float hv[2];
#pragma unroll
      for (int i = 0; i < 2; ++i) act_tuple(accB[i], c_state[1][i], hv[i]);
      unsigned p01 = pk2(hv[0], hv[1]);
      *(unsigned*)&hs[1][nxt][l15][32 + 8 * w + 2 * q] = p01;
    }

    __syncthreads();   // one barrier per step, covers both cohorts
  }

  // ---- FC epilogue: final h in buf 0; 320 outputs, coalesced ---------------
  if (tid < NCOH * RPC * OUT_DIM) {
    const int r = tid / OUT_DIM;        // block-row 0..31
    const int o = tid - r * OUT_DIM;
    const int coh = r >> 4, rr = r & 15;
    float sacc = b_fc[o];
#pragma unroll
    for (int p = 0; p < HID; ++p) {
      const int u = 8 * (p >> 3) + 4 * (p & 1) + ((p >> 1) & 3);  // sigma^-1
      sacc += bf2f(hs[coh][0][rr][32 + p]) * W_fc[o * HID + u];
    }
    out[(size_t)(b0 + r) * OUT_DIM + o] = sacc;
  }
}

extern "C" void kernel_launch(void* const* d_in, const int* in_sizes, int n_in,
                              void* d_out, int out_size, void* d_ws, size_t ws_size,
                              hipStream_t stream) {
  const float* x    = (const float*)d_in[0];
  const float* W_ih = (const float*)d_in[1];
  const float* W_hh = (const float*)d_in[2];
  const float* b_ih = (const float*)d_in[3];
  const float* b_hh = (const float*)d_in[4];
  const float* W_fc = (const float*)d_in[5];
  const float* b_fc = (const float*)d_in[6];
  float* out = (float*)d_out;
  unsigned short* ws = (unsigned short*)d_ws;   // 48 KB frag-ordered weights

  lstm_prep<<<(WS_ELEMS + 255) / 256, 256, 0, stream>>>(W_ih, W_hh, b_ih, b_hh, ws);

  dim3 grid(B_TOT / (NCOH * RPC));  // 512 blocks -> 2 blocks/CU, 8 waves each
  dim3 block(THREADS);
  lstm_mfma13<<<grid, block, 0, stream>>>(x, ws, W_fc, b_fc, out);
}